// Round 12
// baseline (247.385 us; speedup 1.0000x reference)
//
#include <hip/hip_runtime.h>
#include <cstdint>

#define BATCH 4096
#define IN_DIM 1024
#define HID 2048
#define OUT_DIM 10
#define NTASKS 10

typedef __bf16 bf16x8 __attribute__((ext_vector_type(8)));
typedef float f32x4 __attribute__((ext_vector_type(4)));
typedef __attribute__((address_space(3))) uint8_t lds_u8;
typedef const __attribute__((address_space(1))) uint8_t glb_u8;

__device__ __forceinline__ unsigned short f2bf(float f) {
    uint32_t u = __builtin_bit_cast(uint32_t, f);
    u += 0x7fffu + ((u >> 16) & 1u);   // round-to-nearest-even
    return (unsigned short)(u >> 16);
}
__device__ __forceinline__ uint32_t pk(float a, float b) {
    return (uint32_t)f2bf(a) | ((uint32_t)f2bf(b) << 16);
}
__device__ __forceinline__ uint4 cv8(float4 a, float4 b) {
    uint4 r;
    r.x = pk(a.x, a.y); r.y = pk(a.z, a.w);
    r.z = pk(b.x, b.y); r.w = pk(b.z, b.w);
    return r;
}

// ---------------- standalone: w0 transform ----------------
__global__ __launch_bounds__(256) void bl_transform(
    const float4* __restrict__ mu, const float4* __restrict__ ls,
    const float4* __restrict__ eps, uint4* __restrict__ out)
{
    const int t  = threadIdx.x;
    const int fb = blockIdx.x * 1024;
    const int ia = fb + 2 * t;
    const int ib = fb + 512 + 2 * t;
    const float4 m0 = mu[ia], m1 = mu[ia + 1], m2 = mu[ib], m3 = mu[ib + 1];
    const float4 l0 = ls[ia], l1 = ls[ia + 1], l2 = ls[ib], l3 = ls[ib + 1];
    const float4 e0 = eps[ia], e1 = eps[ia + 1], e2 = eps[ib], e3 = eps[ib + 1];
    uint4 o0, o1;
    o0.x = pk(m0.x + __expf(l0.x) * e0.x, m0.y + __expf(l0.y) * e0.y);
    o0.y = pk(m0.z + __expf(l0.z) * e0.z, m0.w + __expf(l0.w) * e0.w);
    o0.z = pk(m1.x + __expf(l1.x) * e1.x, m1.y + __expf(l1.y) * e1.y);
    o0.w = pk(m1.z + __expf(l1.z) * e1.z, m1.w + __expf(l1.w) * e1.w);
    o1.x = pk(m2.x + __expf(l2.x) * e2.x, m2.y + __expf(l2.y) * e2.y);
    o1.y = pk(m2.z + __expf(l2.z) * e2.z, m2.w + __expf(l2.w) * e2.w);
    o1.z = pk(m3.x + __expf(l3.x) * e3.x, m3.y + __expf(l3.y) * e3.y);
    o1.w = pk(m3.z + __expf(l3.z) * e3.z, m3.w + __expf(l3.w) * e3.w);
    out[blockIdx.x * 512 + t]       = o0;
    out[blockIdx.x * 512 + 256 + t] = o1;
}

// biases b0/b1..3 + head bias
__global__ __launch_bounds__(256) void bl_small(
    const float* __restrict__ mu_b0, const float* __restrict__ ls_b0, const float* __restrict__ eps_b0,
    const float* __restrict__ mu_b,  const float* __restrict__ ls_b,  const float* __restrict__ eps_b,
    const float* __restrict__ mu_hb, const float* __restrict__ ls_hb, const float* __restrict__ eps_hb,
    float* __restrict__ b_all, float* __restrict__ hb)
{
    const int total = 4 * HID + NTASKS * OUT_DIM;
    const int i = blockIdx.x * blockDim.x + threadIdx.x;
    if (i >= total) return;
    if (i < HID) {
        b_all[i] = mu_b0[i] + __expf(ls_b0[i]) * eps_b0[i];
    } else if (i < 4 * HID) {
        const int j = i - HID;
        b_all[HID + j] = mu_b[j] + __expf(ls_b[j]) * eps_b[j];
    } else {
        const int j = i - 4 * HID;
        hb[j] = mu_hb[j] + __expf(ls_hb[j]) * eps_hb[j];
    }
}

// ---------------- fused GEMM + pipelined next-layer weight transform --------
// Waves 0-7: round-6-verified GEMM skeleton (BM=256 BN=128 BK=64, 96KB dbuf,
// 4 phases/K-tile, 7xBAR + 1x__syncthreads per tile). AF32: A read as fp32
// and reg-stage-cast to bf16 (kills the standalone x-cvt; round-9-verified).
// Waves 8-9: transform of next layer's weights, SOFTWARE-PIPELINED 2 DEEP so
// no memory op is drained by a syncthreads in its own issue iteration:
//   start of t:  STORE res(t-1)          [floats a full iteration]
//                COMPUTE res(t) from regs loaded at t-2
//                ISSUE loads for t+2     [~2300cy before their drain]
// Round 6 exposed ~1700cy/iter at the drain (its +23us); this removes it
// while keeping the exact barrier sequence (round-7's lesson: counts only).
#define BAR()        asm volatile("s_barrier" ::: "memory")
#define WAIT_LGKM0() do { asm volatile("s_waitcnt lgkmcnt(0)" ::: "memory"); __builtin_amdgcn_sched_barrier(0); } while (0)
#define RD_A(m, o)   (*(const bf16x8*)(ldsb + acur + (o) + (m)*2048))
#define RD_B(n, o)   (*(const bf16x8*)(ldsb + bcur + (o) + (n)*2048))
#define MFMA(d, va, vb) d = __builtin_amdgcn_mfma_f32_16x16x32_bf16(va, vb, d, 0, 0, 0)

template <int UPG, int TMODE, bool AF32>
__global__ __launch_bounds__(640, 1) void bl_gemm(
    const void* __restrict__ Ap,            // bf16 [4096][K] or f32 (AF32)
    const unsigned short* __restrict__ Bw,  // bf16 [2048][K] weights
    const float* __restrict__ bias,         // [2048]
    unsigned short* __restrict__ C,         // [4096][2048] bf16
    int K,
    const float* __restrict__ tmu, const float* __restrict__ tls,
    const float* __restrict__ teps, void* __restrict__ tdst)
{
    __shared__ unsigned short lds[49152];   // 96 KB
    uint8_t* ldsb = (uint8_t*)lds;

    const int tid  = threadIdx.x;
    const int wave = tid >> 6;
    const int lane = tid & 63;
    const int NT = K >> 6;

    if (wave < 8) {
        // ================= GEMM path =================
        const int swz = ((blockIdx.x & 7) << 5) | (blockIdx.x >> 3);
        const int bm = swz >> 4, bn = swz & 15;
        const int wr = wave >> 1, wc = wave & 1;
        const int lr8 = lane >> 3;
        const int ss  = (lane & 7) ^ lr8;
        const int K4  = K >> 2;

        const unsigned short* gA[4];
        const float4* gAf[4];
        #pragma unroll
        for (int i = 0; i < 4; ++i) {
            const int row = bm * 256 + (wave * 4 + i) * 8 + lr8;
            if constexpr (AF32) gAf[i] = (const float4*)Ap + (size_t)row * K4 + ss * 2;
            else                gA[i]  = (const unsigned short*)Ap + (size_t)row * K + ss * 8;
        }
        const unsigned short* gB[2];
        #pragma unroll
        for (int j = 0; j < 2; ++j) {
            const int row = bn * 128 + (wave * 2 + j) * 8 + lr8;
            gB[j] = Bw + (size_t)row * K + ss * 8;
        }
        const uint32_t aWD = (uint32_t)(wave * 4) * 1024u + (uint32_t)lane * 16u;

        auto STAGEA = [&](int i, int kel, int sl) {
            __builtin_amdgcn_global_load_lds((glb_u8*)(gA[i] + kel),
                (lds_u8*)(ldsb + (uint32_t)(wave * 4 + i) * 1024u + (uint32_t)sl * 32768u), 16, 0, 0);
        };
        auto STAGEB = [&](int j, int kel, int sl) {
            __builtin_amdgcn_global_load_lds((glb_u8*)(gB[j] + kel),
                (lds_u8*)(ldsb + 65536u + (uint32_t)(wave * 2 + j) * 1024u + (uint32_t)sl * 16384u), 16, 0, 0);
        };

        const int rA = wr * 64 + (lane & 15);
        const int rB = wc * 64 + (lane & 15);
        const int ks = lane >> 4;
        const uint32_t aoff0 = (uint32_t)(rA * 128 + ((ks       ^ (rA & 7)) * 16));
        const uint32_t aoff1 = (uint32_t)(rA * 128 + (((4 | ks) ^ (rA & 7)) * 16));
        const uint32_t boff0 = (uint32_t)(rB * 128 + ((ks       ^ (rB & 7)) * 16));
        const uint32_t boff1 = (uint32_t)(rB * 128 + (((4 | ks) ^ (rB & 7)) * 16));

        f32x4 acc[4][4] = {};
        float4 Aa[4], Abv[4];

        // ---- prologue: tile 0 -> slot 0 ----
        if constexpr (AF32) {
            #pragma unroll
            for (int i = 0; i < 4; ++i) { Aa[i] = gAf[i][0]; Abv[i] = gAf[i][1]; }
            STAGEB(0, 0, 0); STAGEB(1, 0, 0);
            #pragma unroll
            for (int i = 0; i < 4; ++i)
                *(uint4*)(ldsb + aWD + (uint32_t)i * 1024u) = cv8(Aa[i], Abv[i]);
        } else {
            STAGEA(0, 0, 0); STAGEA(1, 0, 0); STAGEA(2, 0, 0); STAGEA(3, 0, 0);
            STAGEB(0, 0, 0); STAGEB(1, 0, 0);
        }
        __syncthreads();                                         // barrier #0

        for (int t = 0; t < NT; ++t) {
            const int cur = t & 1, nxt = cur ^ 1;
            const uint32_t acur = (uint32_t)cur * 32768u;
            const uint32_t bcur = 65536u + (uint32_t)cur * 16384u;
            const bool pf = (t + 1 < NT);
            const int ktn = (t + 1) << 6;
            const int k4n = (t + 1) * 16;

            bf16x8 a0, a1, a2, a3, b0, b1, b2, b3;

            // phase 0: frags kk=0 rows 0-1; issue B stage (and A gll half)
            a0 = RD_A(0, aoff0); a1 = RD_A(1, aoff0);
            b0 = RD_B(0, boff0); b1 = RD_B(1, boff0); b2 = RD_B(2, boff0); b3 = RD_B(3, boff0);
            if (pf) {
                STAGEB(0, ktn, nxt); STAGEB(1, ktn, nxt);
                if constexpr (!AF32) { STAGEA(0, ktn, nxt); }
            }
            BAR(); WAIT_LGKM0();
            __builtin_amdgcn_s_setprio(1);
            MFMA(acc[0][0], a0, b0); MFMA(acc[0][1], a0, b1); MFMA(acc[0][2], a0, b2); MFMA(acc[0][3], a0, b3);
            MFMA(acc[1][0], a1, b0); MFMA(acc[1][1], a1, b1); MFMA(acc[1][2], a1, b2); MFMA(acc[1][3], a1, b3);
            __builtin_amdgcn_s_setprio(0);
            BAR();

            // phase 1: frags kk=0 rows 2-3; issue A staging
            a2 = RD_A(2, aoff0); a3 = RD_A(3, aoff0);
            if (pf) {
                if constexpr (AF32) {
                    #pragma unroll
                    for (int i = 0; i < 4; ++i) { Aa[i] = gAf[i][k4n]; Abv[i] = gAf[i][k4n + 1]; }
                } else {
                    STAGEA(1, ktn, nxt); STAGEA(2, ktn, nxt); STAGEA(3, ktn, nxt);
                }
            }
            BAR(); WAIT_LGKM0();
            __builtin_amdgcn_s_setprio(1);
            MFMA(acc[2][0], a2, b0); MFMA(acc[2][1], a2, b1); MFMA(acc[2][2], a2, b2); MFMA(acc[2][3], a2, b3);
            MFMA(acc[3][0], a3, b0); MFMA(acc[3][1], a3, b1); MFMA(acc[3][2], a3, b2); MFMA(acc[3][3], a3, b3);
            __builtin_amdgcn_s_setprio(0);
            BAR();

            // phase 2: frags kk=1 rows 0-1
            a0 = RD_A(0, aoff1); a1 = RD_A(1, aoff1);
            b0 = RD_B(0, boff1); b1 = RD_B(1, boff1); b2 = RD_B(2, boff1); b3 = RD_B(3, boff1);
            BAR(); WAIT_LGKM0();
            __builtin_amdgcn_s_setprio(1);
            MFMA(acc[0][0], a0, b0); MFMA(acc[0][1], a0, b1); MFMA(acc[0][2], a0, b2); MFMA(acc[0][3], a0, b3);
            MFMA(acc[1][0], a1, b0); MFMA(acc[1][1], a1, b1); MFMA(acc[1][2], a1, b2); MFMA(acc[1][3], a1, b3);
            __builtin_amdgcn_s_setprio(0);
            BAR();

            // phase 3: frags kk=1 rows 2-3; AF32 A ds_write; dbuf swap drain
            a2 = RD_A(2, aoff1); a3 = RD_A(3, aoff1);
            BAR(); WAIT_LGKM0();
            __builtin_amdgcn_s_setprio(1);
            MFMA(acc[2][0], a2, b0); MFMA(acc[2][1], a2, b1); MFMA(acc[2][2], a2, b2); MFMA(acc[2][3], a2, b3);
            MFMA(acc[3][0], a3, b0); MFMA(acc[3][1], a3, b1); MFMA(acc[3][2], a3, b2); MFMA(acc[3][3], a3, b3);
            __builtin_amdgcn_s_setprio(0);
            if constexpr (AF32) {
                if (pf) {
                    const uint32_t ad = aWD + (uint32_t)nxt * 32768u;
                    #pragma unroll
                    for (int i = 0; i < 4; ++i)
                        *(uint4*)(ldsb + ad + (uint32_t)i * 1024u) = cv8(Aa[i], Abv[i]);
                }
            }
            __syncthreads();
        }

        // epilogue
        const int col0 = bn * 128 + wc * 64 + (lane & 15);
        const int row0 = bm * 256 + wr * 64 + ((lane >> 4) << 2);
        #pragma unroll
        for (int n = 0; n < 4; ++n) {
            const int col = col0 + n * 16;
            const float bv = bias[col];
            #pragma unroll
            for (int m = 0; m < 4; ++m) {
                #pragma unroll
                for (int j = 0; j < 4; ++j) {
                    float v = acc[m][n][j] + bv;
                    v = v > 0.0f ? v : 0.0f;
                    C[(size_t)(row0 + m * 16 + j) * HID + col] = f2bf(v);
                }
            }
        }
    } else {
        // ================= transform path (waves 8-9, 128 threads) ===========
        const int tw = tid - 512;
        if constexpr (TMODE == 0) {
            const float4* m4 = (const float4*)tmu;
            const float4* l4 = (const float4*)tls;
            const float4* e4 = (const float4*)teps;
            ushort4* d4 = (ushort4*)tdst;
            const uint32_t base = (uint32_t)blockIdx.x * 4096u + (uint32_t)tw;

            float4 mA[UPG], lA[UPG], eA[UPG], mB[UPG], lB[UPG], eB[UPG];
            ushort4 rsA[UPG], rsB[UPG];

            auto LD = [&](int t, float4* m, float4* l, float4* e) {
                if (t < NT) {
                    #pragma unroll
                    for (int q = 0; q < UPG; ++q) {
                        const uint32_t g = base + (uint32_t)(t * UPG + q) * 128u;
                        m[q] = m4[g]; l[q] = l4[g]; e[q] = e4[g];
                    }
                }
            };
            auto CP = [&](float4* m, float4* l, float4* e, ushort4* r) {
                #pragma unroll
                for (int q = 0; q < UPG; ++q) {
                    r[q].x = f2bf(m[q].x + __expf(l[q].x) * e[q].x);
                    r[q].y = f2bf(m[q].y + __expf(l[q].y) * e[q].y);
                    r[q].z = f2bf(m[q].z + __expf(l[q].z) * e[q].z);
                    r[q].w = f2bf(m[q].w + __expf(l[q].w) * e[q].w);
                }
            };
            auto ST = [&](int t, ushort4* r) {
                #pragma unroll
                for (int q = 0; q < UPG; ++q)
                    d4[base + (uint32_t)(t * UPG + q) * 128u] = r[q];
            };

            LD(0, mA, lA, eA); LD(1, mB, lB, eB);
            __syncthreads();                           // matches barrier #0
            for (int t = 0; t < NT; t += 2) {
                // even iteration t (set A)
                if (t > 0) ST(t - 1, rsB);             // floats through this iter
                CP(mA, lA, eA, rsA);
                LD(t + 2, mA, lA, eA);                 // ~2300cy before drain
                BAR(); BAR(); BAR(); BAR(); BAR(); BAR(); BAR();
                __syncthreads();
                // odd iteration t+1 (set B)
                ST(t, rsA);
                CP(mB, lB, eB, rsB);
                LD(t + 3, mB, lB, eB);
                BAR(); BAR(); BAR(); BAR(); BAR(); BAR(); BAR();
                __syncthreads();
            }
            ST(NT - 1, rsB);                           // after final sync; no more barriers
        } else {
            // head weights -> f32, 200 float4-units/block over iters 0-1
            const float4* m4 = (const float4*)tmu;
            const float4* l4 = (const float4*)tls;
            const float4* e4 = (const float4*)teps;
            float4* o4 = (float4*)tdst;
            const uint32_t b0i = (uint32_t)blockIdx.x * 200u + (uint32_t)tw;
            float4 m0 = m4[b0i], l0 = l4[b0i], e0 = e4[b0i];
            float4 m1, l1, e1;
            if (tw < 72) { m1 = m4[b0i + 128]; l1 = l4[b0i + 128]; e1 = e4[b0i + 128]; }
            __syncthreads();
            float4 r0, r1;
            for (int t = 0; t < NT; ++t) {
                if (t == 0) {
                    r0.x = m0.x + __expf(l0.x) * e0.x;
                    r0.y = m0.y + __expf(l0.y) * e0.y;
                    r0.z = m0.z + __expf(l0.z) * e0.z;
                    r0.w = m0.w + __expf(l0.w) * e0.w;
                    if (tw < 72) {
                        r1.x = m1.x + __expf(l1.x) * e1.x;
                        r1.y = m1.y + __expf(l1.y) * e1.y;
                        r1.z = m1.z + __expf(l1.z) * e1.z;
                        r1.w = m1.w + __expf(l1.w) * e1.w;
                    }
                } else if (t == 1) {
                    o4[b0i] = r0;
                } else if (t == 2) {
                    if (tw < 72) o4[b0i + 128] = r1;
                }
                BAR(); BAR(); BAR(); BAR(); BAR(); BAR(); BAR();
                __syncthreads();
            }
        }
    }
}

// ---------------- head ----------------
__global__ __launch_bounds__(256) void bl_head(
    const unsigned short* __restrict__ h,   // [4096][2048] bf16
    const float* __restrict__ hw,           // [10][10][2048] f32
    const float* __restrict__ hb,           // [10][10] f32
    const int* __restrict__ task,           // [4096] i32
    float* __restrict__ out)                // [4096][10] f32
{
    const int wave = threadIdx.x >> 6, lane = threadIdx.x & 63;
    const int b = blockIdx.x * 4 + wave;
    const int t = task[b];
    const float* w = hw + (size_t)t * OUT_DIM * HID;
    const unsigned short* hr = h + (size_t)b * HID;

    float acc[OUT_DIM];
    #pragma unroll
    for (int o = 0; o < OUT_DIM; ++o) acc[o] = 0.0f;

    #pragma unroll
    for (int i = 0; i < HID / 512; ++i) {
        const int k0 = (i * 64 + lane) * 8;
        const bf16x8 hv8 = *(const bf16x8*)(hr + k0);
        float hf[8];
        #pragma unroll
        for (int j = 0; j < 8; ++j) hf[j] = (float)hv8[j];
        #pragma unroll
        for (int o = 0; o < OUT_DIM; ++o) {
            const float4 w0 = *(const float4*)(w + (size_t)o * HID + k0);
            const float4 w1 = *(const float4*)(w + (size_t)o * HID + k0 + 4);
            acc[o] += hf[0]*w0.x + hf[1]*w0.y + hf[2]*w0.z + hf[3]*w0.w
                    + hf[4]*w1.x + hf[5]*w1.y + hf[6]*w1.z + hf[7]*w1.w;
        }
    }
    #pragma unroll
    for (int o = 0; o < OUT_DIM; ++o) {
        float v = acc[o];
        #pragma unroll
        for (int s = 32; s > 0; s >>= 1) v += __shfl_down(v, s, 64);
        if (lane == 0) out[(size_t)b * OUT_DIM + o] = v + hb[t * OUT_DIM + o];
    }
}

// ---------------- launch ----------------

extern "C" void kernel_launch(void* const* d_in, const int* in_sizes, int n_in,
                              void* d_out, int out_size, void* d_ws, size_t ws_size,
                              hipStream_t stream)
{
    const float* x      = (const float*)d_in[0];
    const float* mu_w0  = (const float*)d_in[1];
    const float* ls_w0  = (const float*)d_in[2];
    const float* mu_b0  = (const float*)d_in[3];
    const float* ls_b0  = (const float*)d_in[4];
    const float* mu_w   = (const float*)d_in[5];
    const float* ls_w   = (const float*)d_in[6];
    const float* mu_b   = (const float*)d_in[7];
    const float* ls_b   = (const float*)d_in[8];
    const float* mu_hw  = (const float*)d_in[9];
    const float* ls_hw  = (const float*)d_in[10];
    const float* mu_hb  = (const float*)d_in[11];
    const float* ls_hb  = (const float*)d_in[12];
    const float* eps_w0 = (const float*)d_in[13];
    const float* eps_b0 = (const float*)d_in[14];
    const float* eps_w  = (const float*)d_in[15];
    const float* eps_b  = (const float*)d_in[16];
    const float* eps_hw = (const float*)d_in[17];
    const float* eps_hb = (const float*)d_in[18];
    const int*   task   = (const int*)d_in[19];

    uint8_t* ws = (uint8_t*)d_ws;
    constexpr size_t HH     = (size_t)HID * HID;
    constexpr size_t W0_OFF = 0;                                     // w0 bf16
    constexpr size_t W_OFF  = W0_OFF + (size_t)HID * IN_DIM * 2;     // w1..3 bf16
    constexpr size_t H0_OFF = W_OFF  + 3 * HH * 2;                   // h ping
    constexpr size_t H1_OFF = H0_OFF + (size_t)BATCH * HID * 2;      // h pong
    constexpr size_t B_OFF  = H1_OFF + (size_t)BATCH * HID * 2;      // biases f32
    constexpr size_t HW_OFF = B_OFF  + (size_t)4 * HID * 4;          // head w f32
    constexpr size_t HB_OFF = HW_OFF + (size_t)NTASKS * OUT_DIM * HID * 4;

    unsigned short* w0b = (unsigned short*)(ws + W0_OFF);
    unsigned short* wb  = (unsigned short*)(ws + W_OFF);
    unsigned short* h0  = (unsigned short*)(ws + H0_OFF);
    unsigned short* h1  = (unsigned short*)(ws + H1_OFF);
    float* ball = (float*)(ws + B_OFF);
    float* hwf  = (float*)(ws + HW_OFF);
    float* hbf  = (float*)(ws + HB_OFF);

    bl_transform<<<HID * IN_DIM / 4096, 256, 0, stream>>>(
        (const float4*)mu_w0, (const float4*)ls_w0, (const float4*)eps_w0, (uint4*)w0b);
    bl_small<<<(4 * HID + NTASKS * OUT_DIM + 255) / 256, 256, 0, stream>>>(
        mu_b0, ls_b0, eps_b0, mu_b, ls_b, eps_b, mu_hb, ls_hb, eps_hb, ball, hbf);

    // GEMM_i fuses transform of layer i+1's weights (or head weights in G3).
    bl_gemm<2, 0, true><<<256, 640, 0, stream>>>(
        x, w0b, ball, h0, IN_DIM, mu_w, ls_w, eps_w, (void*)wb);           // w1
    bl_gemm<1, 0, false><<<256, 640, 0, stream>>>(
        h0, wb, ball + HID, h1, HID,
        mu_w + HH, ls_w + HH, eps_w + HH, (void*)(wb + HH));               // w2
    bl_gemm<1, 0, false><<<256, 640, 0, stream>>>(
        h1, wb + HH, ball + 2 * HID, h0, HID,
        mu_w + 2 * HH, ls_w + 2 * HH, eps_w + 2 * HH, (void*)(wb + 2 * HH)); // w3
    bl_gemm<1, 1, false><<<256, 640, 0, stream>>>(
        h0, wb + 2 * HH, ball + 3 * HID, h1, HID,
        mu_hw, ls_hw, eps_hw, (void*)hwf);                                 // head w

    bl_head<<<BATCH / 4, 256, 0, stream>>>(h1, hwf, hbf, task, (float*)d_out);
}

// Round 13
// 210.989 us; speedup vs baseline: 1.1725x; 1.1725x over previous
//
#include <hip/hip_runtime.h>
#include <cstdint>

#define BATCH 4096
#define IN_DIM 1024
#define HID 2048
#define OUT_DIM 10
#define NTASKS 10

typedef __bf16 bf16x8 __attribute__((ext_vector_type(8)));
typedef float f32x4 __attribute__((ext_vector_type(4)));
typedef __attribute__((address_space(3))) uint8_t lds_u8;
typedef const __attribute__((address_space(1))) uint8_t glb_u8;

__device__ __forceinline__ unsigned short f2bf(float f) {
    uint32_t u = __builtin_bit_cast(uint32_t, f);
    u += 0x7fffu + ((u >> 16) & 1u);   // round-to-nearest-even
    return (unsigned short)(u >> 16);
}
__device__ __forceinline__ uint32_t pk(float a, float b) {
    return (uint32_t)f2bf(a) | ((uint32_t)f2bf(b) << 16);
}

// ---------------- standalone transforms (pre-GEMM0 inputs only) ----------------

__global__ __launch_bounds__(256) void bl_transform(
    const float4* __restrict__ mu, const float4* __restrict__ ls,
    const float4* __restrict__ eps, uint4* __restrict__ out)
{
    const int t  = threadIdx.x;
    const int fb = blockIdx.x * 1024;
    const int ia = fb + 2 * t;
    const int ib = fb + 512 + 2 * t;
    const float4 m0 = mu[ia], m1 = mu[ia + 1], m2 = mu[ib], m3 = mu[ib + 1];
    const float4 l0 = ls[ia], l1 = ls[ia + 1], l2 = ls[ib], l3 = ls[ib + 1];
    const float4 e0 = eps[ia], e1 = eps[ia + 1], e2 = eps[ib], e3 = eps[ib + 1];
    uint4 o0, o1;
    o0.x = pk(m0.x + __expf(l0.x) * e0.x, m0.y + __expf(l0.y) * e0.y);
    o0.y = pk(m0.z + __expf(l0.z) * e0.z, m0.w + __expf(l0.w) * e0.w);
    o0.z = pk(m1.x + __expf(l1.x) * e1.x, m1.y + __expf(l1.y) * e1.y);
    o0.w = pk(m1.z + __expf(l1.z) * e1.z, m1.w + __expf(l1.w) * e1.w);
    o1.x = pk(m2.x + __expf(l2.x) * e2.x, m2.y + __expf(l2.y) * e2.y);
    o1.y = pk(m2.z + __expf(l2.z) * e2.z, m2.w + __expf(l2.w) * e2.w);
    o1.z = pk(m3.x + __expf(l3.x) * e3.x, m3.y + __expf(l3.y) * e3.y);
    o1.w = pk(m3.z + __expf(l3.z) * e3.z, m3.w + __expf(l3.w) * e3.w);
    out[blockIdx.x * 512 + t]       = o0;
    out[blockIdx.x * 512 + 256 + t] = o1;
}

__global__ __launch_bounds__(256) void bl_cvt(
    const float4* __restrict__ in, uint4* __restrict__ out)
{
    const int t  = threadIdx.x;
    const int fb = blockIdx.x * 1024;
    const int ia = fb + 2 * t;
    const int ib = fb + 512 + 2 * t;
    const float4 v0 = in[ia], v1 = in[ia + 1], v2 = in[ib], v3 = in[ib + 1];
    uint4 o0, o1;
    o0.x = pk(v0.x, v0.y); o0.y = pk(v0.z, v0.w);
    o0.z = pk(v1.x, v1.y); o0.w = pk(v1.z, v1.w);
    o1.x = pk(v2.x, v2.y); o1.y = pk(v2.z, v2.w);
    o1.z = pk(v3.x, v3.y); o1.w = pk(v3.z, v3.w);
    out[blockIdx.x * 512 + t]       = o0;
    out[blockIdx.x * 512 + 256 + t] = o1;
}

// biases only: b0 (HID), b1..3 (3*HID), hb (100)
__global__ __launch_bounds__(256) void bl_small(
    const float* __restrict__ mu_b0, const float* __restrict__ ls_b0, const float* __restrict__ eps_b0,
    const float* __restrict__ mu_b,  const float* __restrict__ ls_b,  const float* __restrict__ eps_b,
    const float* __restrict__ mu_hb, const float* __restrict__ ls_hb, const float* __restrict__ eps_hb,
    float* __restrict__ b_all, float* __restrict__ hb)
{
    const int total = 4 * HID + NTASKS * OUT_DIM;
    const int i = blockIdx.x * blockDim.x + threadIdx.x;
    if (i >= total) return;
    if (i < HID) {
        b_all[i] = mu_b0[i] + __expf(ls_b0[i]) * eps_b0[i];
    } else if (i < 4 * HID) {
        const int j = i - HID;
        b_all[HID + j] = mu_b[j] + __expf(ls_b[j]) * eps_b[j];
    } else {
        const int j = i - 4 * HID;
        hb[j] = mu_hb[j] + __expf(ls_hb[j]) * eps_hb[j];
    }
}

// ---------------- fused GEMM + next-layer weight transform ----------------
// Waves 0-7: round-6-verified GEMM (BM=256 BN=128 BK=64, 96KB dbuf, 4 phases,
// 7xBAR + 1x__syncthreads per K-tile). Waves 8-9: next layer's weight
// transform, 1-DEEP compile-time ping-pong (R13): at iteration t, issue loads
// for t+1 FIRST (sched_barrier-pinned at the top -> ~2300cy before their
// drain), then compute+store tile t from the set loaded one iteration ago
// (landed; no stall), then the matching barrier sequence. No register copy
// (R7's mistake), no carried stores / double state (R12's spill). Spill
// guard: WRITE_SIZE must stay ~24.6MB.
#define BAR()        asm volatile("s_barrier" ::: "memory")
#define WAIT_LGKM0() do { asm volatile("s_waitcnt lgkmcnt(0)" ::: "memory"); __builtin_amdgcn_sched_barrier(0); } while (0)
#define RD_A(m, o)   (*(const bf16x8*)(ldsb + acur + (o) + (m)*2048))
#define RD_B(n, o)   (*(const bf16x8*)(ldsb + bcur + (o) + (n)*2048))
#define MFMA(d, va, vb) d = __builtin_amdgcn_mfma_f32_16x16x32_bf16(va, vb, d, 0, 0, 0)
#define STAGEI(i, kel, sl) \
    __builtin_amdgcn_global_load_lds((glb_u8*)(gsrc[i] + (kel)), \
        (lds_u8*)(ldsb + ldst[i] + (uint32_t)(sl) * smul[i]), 16, 0, 0)

template <int UPG, int TMODE>
__global__ __launch_bounds__(640, 1) void bl_gemm(
    const unsigned short* __restrict__ A,   // [4096][K] bf16
    const unsigned short* __restrict__ B,   // [2048][K] bf16
    const float* __restrict__ bias,         // [2048]
    unsigned short* __restrict__ C,         // [4096][2048] bf16
    int K,
    const float* __restrict__ tmu, const float* __restrict__ tls,
    const float* __restrict__ teps, void* __restrict__ tdst)
{
    __shared__ unsigned short lds[49152];   // 96 KB
    uint8_t* ldsb = (uint8_t*)lds;

    const int tid  = threadIdx.x;
    const int wave = tid >> 6;
    const int lane = tid & 63;
    const int NT = K >> 6;

    if (wave < 8) {
        // ================= GEMM path (waves 0-7), round-6 verbatim ===========
        const int swz = ((blockIdx.x & 7) << 5) | (blockIdx.x >> 3);
        const int bm = swz >> 4;
        const int bn = swz & 15;
        const int wr = wave >> 1;
        const int wc = wave & 1;

        const int lr8 = lane >> 3;
        const int ss  = (lane & 7) ^ lr8;
        const unsigned short* gsrc[6];
        uint32_t ldst[6], smul[6];
        #pragma unroll
        for (int i = 0; i < 6; ++i) {
            const int c = wave * 6 + i;
            if (c < 32) {
                gsrc[i] = A + (size_t)(bm * 256 + c * 8 + lr8) * K + ss * 8;
                ldst[i] = (uint32_t)c * 1024u;
                smul[i] = 32768u;
            } else {
                gsrc[i] = B + (size_t)(bn * 128 + (c - 32) * 8 + lr8) * K + ss * 8;
                ldst[i] = 65536u + (uint32_t)(c - 32) * 1024u;
                smul[i] = 16384u;
            }
        }

        const int rA = wr * 64 + (lane & 15);
        const int rB = wc * 64 + (lane & 15);
        const int ks = lane >> 4;
        const uint32_t aoff0 = (uint32_t)(rA * 128 + ((ks       ^ (rA & 7)) * 16));
        const uint32_t aoff1 = (uint32_t)(rA * 128 + (((4 | ks) ^ (rA & 7)) * 16));
        const uint32_t boff0 = (uint32_t)(rB * 128 + ((ks       ^ (rB & 7)) * 16));
        const uint32_t boff1 = (uint32_t)(rB * 128 + (((4 | ks) ^ (rB & 7)) * 16));

        f32x4 acc[4][4] = {};

        STAGEI(0, 0, 0); STAGEI(1, 0, 0); STAGEI(2, 0, 0);
        STAGEI(3, 0, 0); STAGEI(4, 0, 0); STAGEI(5, 0, 0);
        __syncthreads();                                         // barrier #0

        for (int t = 0; t < NT; ++t) {
            const int cur = t & 1, nxt = cur ^ 1;
            const uint32_t acur = (uint32_t)cur * 32768u;
            const uint32_t bcur = 65536u + (uint32_t)cur * 16384u;
            const bool pf = (t + 1 < NT);
            const int ktn = (t + 1) << 6;

            bf16x8 a0, a1, a2, a3, b0, b1, b2, b3;

            // phase 0 (BAR x2)
            a0 = RD_A(0, aoff0); a1 = RD_A(1, aoff0);
            b0 = RD_B(0, boff0); b1 = RD_B(1, boff0); b2 = RD_B(2, boff0); b3 = RD_B(3, boff0);
            if (pf) { STAGEI(0, ktn, nxt); STAGEI(1, ktn, nxt); STAGEI(2, ktn, nxt); }
            BAR(); WAIT_LGKM0();
            __builtin_amdgcn_s_setprio(1);
            MFMA(acc[0][0], a0, b0); MFMA(acc[0][1], a0, b1); MFMA(acc[0][2], a0, b2); MFMA(acc[0][3], a0, b3);
            MFMA(acc[1][0], a1, b0); MFMA(acc[1][1], a1, b1); MFMA(acc[1][2], a1, b2); MFMA(acc[1][3], a1, b3);
            __builtin_amdgcn_s_setprio(0);
            BAR();

            // phase 1 (BAR x2)
            a2 = RD_A(2, aoff0); a3 = RD_A(3, aoff0);
            if (pf) { STAGEI(3, ktn, nxt); STAGEI(4, ktn, nxt); STAGEI(5, ktn, nxt); }
            BAR(); WAIT_LGKM0();
            __builtin_amdgcn_s_setprio(1);
            MFMA(acc[2][0], a2, b0); MFMA(acc[2][1], a2, b1); MFMA(acc[2][2], a2, b2); MFMA(acc[2][3], a2, b3);
            MFMA(acc[3][0], a3, b0); MFMA(acc[3][1], a3, b1); MFMA(acc[3][2], a3, b2); MFMA(acc[3][3], a3, b3);
            __builtin_amdgcn_s_setprio(0);
            BAR();

            // phase 2 (BAR x2)
            a0 = RD_A(0, aoff1); a1 = RD_A(1, aoff1);
            b0 = RD_B(0, boff1); b1 = RD_B(1, boff1); b2 = RD_B(2, boff1); b3 = RD_B(3, boff1);
            BAR(); WAIT_LGKM0();
            __builtin_amdgcn_s_setprio(1);
            MFMA(acc[0][0], a0, b0); MFMA(acc[0][1], a0, b1); MFMA(acc[0][2], a0, b2); MFMA(acc[0][3], a0, b3);
            MFMA(acc[1][0], a1, b0); MFMA(acc[1][1], a1, b1); MFMA(acc[1][2], a1, b2); MFMA(acc[1][3], a1, b3);
            __builtin_amdgcn_s_setprio(0);
            BAR();

            // phase 3 (BAR x1 + syncthreads)
            a2 = RD_A(2, aoff1); a3 = RD_A(3, aoff1);
            BAR(); WAIT_LGKM0();
            __builtin_amdgcn_s_setprio(1);
            MFMA(acc[2][0], a2, b0); MFMA(acc[2][1], a2, b1); MFMA(acc[2][2], a2, b2); MFMA(acc[2][3], a2, b3);
            MFMA(acc[3][0], a3, b0); MFMA(acc[3][1], a3, b1); MFMA(acc[3][2], a3, b2); MFMA(acc[3][3], a3, b3);
            __builtin_amdgcn_s_setprio(0);
            __syncthreads();
        }

        // epilogue
        const int col0 = bn * 128 + wc * 64 + (lane & 15);
        const int row0 = bm * 256 + wr * 64 + ((lane >> 4) << 2);
        #pragma unroll
        for (int n = 0; n < 4; ++n) {
            const int col = col0 + n * 16;
            const float bv = bias[col];
            #pragma unroll
            for (int m = 0; m < 4; ++m) {
                #pragma unroll
                for (int j = 0; j < 4; ++j) {
                    float v = acc[m][n][j] + bv;
                    v = v > 0.0f ? v : 0.0f;
                    C[(size_t)(row0 + m * 16 + j) * HID + col] = f2bf(v);
                }
            }
        }
    } else {
        // ========= transform path (waves 8-9, 128 threads), R13 1-deep =======
        const int tw = tid - 512;                      // 0..127
        const float4* m4 = (const float4*)tmu;
        const float4* l4 = (const float4*)tls;
        const float4* e4 = (const float4*)teps;

        if (TMODE == 0) {
            ushort4* d4 = (ushort4*)tdst;
            const size_t base = (size_t)blockIdx.x * 4096;

            float4 mA[UPG], lA[UPG], eA[UPG], mB[UPG], lB[UPG], eB[UPG];

            #define TLOAD(tt, M, L, E)                                           \
                if ((tt) < NT) {                                                 \
                    _Pragma("unroll")                                            \
                    for (int q = 0; q < UPG; ++q) {                              \
                        const size_t g = base + ((size_t)(tt) * UPG + q) * 128 + tw; \
                        M[q] = m4[g]; L[q] = l4[g]; E[q] = e4[g];                \
                    }                                                            \
                }
            #define TSTORE(tt, M, L, E)                                          \
                {                                                                \
                    _Pragma("unroll")                                            \
                    for (int q = 0; q < UPG; ++q) {                              \
                        ushort4 r;                                               \
                        r.x = f2bf(M[q].x + __expf(L[q].x) * E[q].x);            \
                        r.y = f2bf(M[q].y + __expf(L[q].y) * E[q].y);            \
                        r.z = f2bf(M[q].z + __expf(L[q].z) * E[q].z);            \
                        r.w = f2bf(M[q].w + __expf(L[q].w) * E[q].w);            \
                        d4[base + ((size_t)(tt) * UPG + q) * 128 + tw] = r;      \
                    }                                                            \
                }

            TLOAD(0, mA, lA, eA);
            __syncthreads();                           // matches barrier #0

            for (int t = 0; t < NT; t += 2) {
                // even tile t: issue loads(t+1) first, consume set A
                TLOAD(t + 1, mB, lB, eB);
                __builtin_amdgcn_sched_barrier(0);     // pin load issue at top
                TSTORE(t, mA, lA, eA);
                BAR(); BAR(); BAR(); BAR(); BAR(); BAR(); BAR();
                __syncthreads();
                // odd tile t+1: issue loads(t+2), consume set B
                TLOAD(t + 2, mA, lA, eA);
                __builtin_amdgcn_sched_barrier(0);
                TSTORE(t + 1, mB, lB, eB);
                BAR(); BAR(); BAR(); BAR(); BAR(); BAR(); BAR();
                __syncthreads();
            }
            #undef TLOAD
            #undef TSTORE
        } else {
            // head weights -> f32 (round-6 verbatim): 200 units/block
            const size_t base = (size_t)blockIdx.x * 200;
            __syncthreads();                           // matches barrier #0
            for (int t = 0; t < NT; ++t) {
                const int lo = t * 128 + tw;
                if (lo < 200) {
                    const size_t g = base + lo;
                    const float4 m = m4[g], l = l4[g], e = e4[g];
                    float4 r;
                    r.x = m.x + __expf(l.x) * e.x;
                    r.y = m.y + __expf(l.y) * e.y;
                    r.z = m.z + __expf(l.z) * e.z;
                    r.w = m.w + __expf(l.w) * e.w;
                    ((float4*)tdst)[g] = r;
                }
                BAR(); BAR(); BAR(); BAR(); BAR(); BAR(); BAR();
                __syncthreads();
            }
        }
    }
}

// ---------------- head ----------------
__global__ __launch_bounds__(256) void bl_head(
    const unsigned short* __restrict__ h,   // [4096][2048] bf16
    const float* __restrict__ hw,           // [10][10][2048] f32
    const float* __restrict__ hb,           // [10][10] f32
    const int* __restrict__ task,           // [4096] i32
    float* __restrict__ out)                // [4096][10] f32
{
    const int wave = threadIdx.x >> 6, lane = threadIdx.x & 63;
    const int b = blockIdx.x * 4 + wave;
    const int t = task[b];
    const float* w = hw + (size_t)t * OUT_DIM * HID;
    const unsigned short* hr = h + (size_t)b * HID;

    float acc[OUT_DIM];
    #pragma unroll
    for (int o = 0; o < OUT_DIM; ++o) acc[o] = 0.0f;

    #pragma unroll
    for (int i = 0; i < HID / 512; ++i) {
        const int k0 = (i * 64 + lane) * 8;
        const bf16x8 hv8 = *(const bf16x8*)(hr + k0);
        float hf[8];
        #pragma unroll
        for (int j = 0; j < 8; ++j) hf[j] = (float)hv8[j];
        #pragma unroll
        for (int o = 0; o < OUT_DIM; ++o) {
            const float4 w0 = *(const float4*)(w + (size_t)o * HID + k0);
            const float4 w1 = *(const float4*)(w + (size_t)o * HID + k0 + 4);
            acc[o] += hf[0]*w0.x + hf[1]*w0.y + hf[2]*w0.z + hf[3]*w0.w
                    + hf[4]*w1.x + hf[5]*w1.y + hf[6]*w1.z + hf[7]*w1.w;
        }
    }
    #pragma unroll
    for (int o = 0; o < OUT_DIM; ++o) {
        float v = acc[o];
        #pragma unroll
        for (int s = 32; s > 0; s >>= 1) v += __shfl_down(v, s, 64);
        if (lane == 0) out[(size_t)b * OUT_DIM + o] = v + hb[t * OUT_DIM + o];
    }
}

// ---------------- launch ----------------

extern "C" void kernel_launch(void* const* d_in, const int* in_sizes, int n_in,
                              void* d_out, int out_size, void* d_ws, size_t ws_size,
                              hipStream_t stream)
{
    const float* x      = (const float*)d_in[0];
    const float* mu_w0  = (const float*)d_in[1];
    const float* ls_w0  = (const float*)d_in[2];
    const float* mu_b0  = (const float*)d_in[3];
    const float* ls_b0  = (const float*)d_in[4];
    const float* mu_w   = (const float*)d_in[5];
    const float* ls_w   = (const float*)d_in[6];
    const float* mu_b   = (const float*)d_in[7];
    const float* ls_b   = (const float*)d_in[8];
    const float* mu_hw  = (const float*)d_in[9];
    const float* ls_hw  = (const float*)d_in[10];
    const float* mu_hb  = (const float*)d_in[11];
    const float* ls_hb  = (const float*)d_in[12];
    const float* eps_w0 = (const float*)d_in[13];
    const float* eps_b0 = (const float*)d_in[14];
    const float* eps_w  = (const float*)d_in[15];
    const float* eps_b  = (const float*)d_in[16];
    const float* eps_hw = (const float*)d_in[17];
    const float* eps_hb = (const float*)d_in[18];
    const int*   task   = (const int*)d_in[19];

    uint8_t* ws = (uint8_t*)d_ws;
    constexpr size_t HH     = (size_t)HID * HID;
    constexpr size_t X_OFF  = 0;
    constexpr size_t W0_OFF = X_OFF  + (size_t)BATCH * IN_DIM * 2;       // x bf16
    constexpr size_t W_OFF  = W0_OFF + (size_t)HID * IN_DIM * 2;         // w0 bf16
    constexpr size_t H0_OFF = W_OFF  + 3 * HH * 2;                       // w1..3 bf16
    constexpr size_t H1_OFF = H0_OFF + (size_t)BATCH * HID * 2;          // h ping
    constexpr size_t B_OFF  = H1_OFF + (size_t)BATCH * HID * 2;          // h pong
    constexpr size_t HW_OFF = B_OFF  + (size_t)4 * HID * 4;              // biases f32
    constexpr size_t HB_OFF = HW_OFF + (size_t)NTASKS * OUT_DIM * HID * 4;

    unsigned short* xbf = (unsigned short*)(ws + X_OFF);
    unsigned short* w0b = (unsigned short*)(ws + W0_OFF);
    unsigned short* wb  = (unsigned short*)(ws + W_OFF);
    unsigned short* h0  = (unsigned short*)(ws + H0_OFF);
    unsigned short* h1  = (unsigned short*)(ws + H1_OFF);
    float* ball = (float*)(ws + B_OFF);
    float* hwf  = (float*)(ws + HW_OFF);
    float* hbf  = (float*)(ws + HB_OFF);

    bl_cvt<<<BATCH * IN_DIM / 4096, 256, 0, stream>>>((const float4*)x, (uint4*)xbf);
    bl_transform<<<HID * IN_DIM / 4096, 256, 0, stream>>>(
        (const float4*)mu_w0, (const float4*)ls_w0, (const float4*)eps_w0, (uint4*)w0b);
    bl_small<<<(4 * HID + NTASKS * OUT_DIM + 255) / 256, 256, 0, stream>>>(
        mu_b0, ls_b0, eps_b0, mu_b, ls_b, eps_b, mu_hb, ls_hb, eps_hb, ball, hbf);

    // GEMM_i fuses the transform of layer i+1's weights (or head weights).
    bl_gemm<2, 0><<<256, 640, 0, stream>>>(xbf, w0b, ball, h0, IN_DIM,
        mu_w, ls_w, eps_w, (void*)wb);                               // w1 (NT=16, upg=2)
    bl_gemm<1, 0><<<256, 640, 0, stream>>>(h0, wb, ball + HID, h1, HID,
        mu_w + HH, ls_w + HH, eps_w + HH, (void*)(wb + HH));         // w2
    bl_gemm<1, 0><<<256, 640, 0, stream>>>(h1, wb + HH, ball + 2 * HID, h0, HID,
        mu_w + 2 * HH, ls_w + 2 * HH, eps_w + 2 * HH, (void*)(wb + 2 * HH)); // w3
    bl_gemm<1, 1><<<256, 640, 0, stream>>>(h0, wb + 2 * HH, ball + 3 * HID, h1, HID,
        mu_hw, ls_hw, eps_hw, (void*)hwf);                           // head weights f32

    bl_head<<<BATCH / 4, 256, 0, stream>>>(h1, hwf, hbf, task, (float*)d_out);
}

// Round 14
// 200.032 us; speedup vs baseline: 1.2367x; 1.0548x over previous
//
#include <hip/hip_runtime.h>
#include <cstdint>

#define BATCH 4096
#define IN_DIM 1024
#define HID 2048
#define OUT_DIM 10
#define NTASKS 10

typedef __bf16 bf16x8 __attribute__((ext_vector_type(8)));
typedef float f32x4 __attribute__((ext_vector_type(4)));
typedef __attribute__((address_space(3))) uint8_t lds_u8;
typedef const __attribute__((address_space(1))) uint8_t glb_u8;

__device__ __forceinline__ unsigned short f2bf(float f) {
    uint32_t u = __builtin_bit_cast(uint32_t, f);
    u += 0x7fffu + ((u >> 16) & 1u);   // round-to-nearest-even
    return (unsigned short)(u >> 16);
}
__device__ __forceinline__ uint32_t pk(float a, float b) {
    return (uint32_t)f2bf(a) | ((uint32_t)f2bf(b) << 16);
}

// ---------------- standalone transforms (pre-GEMM0 inputs only) ----------------

__global__ __launch_bounds__(256) void bl_transform(
    const float4* __restrict__ mu, const float4* __restrict__ ls,
    const float4* __restrict__ eps, uint4* __restrict__ out)
{
    const int t  = threadIdx.x;
    const int fb = blockIdx.x * 1024;
    const int ia = fb + 2 * t;
    const int ib = fb + 512 + 2 * t;
    const float4 m0 = mu[ia], m1 = mu[ia + 1], m2 = mu[ib], m3 = mu[ib + 1];
    const float4 l0 = ls[ia], l1 = ls[ia + 1], l2 = ls[ib], l3 = ls[ib + 1];
    const float4 e0 = eps[ia], e1 = eps[ia + 1], e2 = eps[ib], e3 = eps[ib + 1];
    uint4 o0, o1;
    o0.x = pk(m0.x + __expf(l0.x) * e0.x, m0.y + __expf(l0.y) * e0.y);
    o0.y = pk(m0.z + __expf(l0.z) * e0.z, m0.w + __expf(l0.w) * e0.w);
    o0.z = pk(m1.x + __expf(l1.x) * e1.x, m1.y + __expf(l1.y) * e1.y);
    o0.w = pk(m1.z + __expf(l1.z) * e1.z, m1.w + __expf(l1.w) * e1.w);
    o1.x = pk(m2.x + __expf(l2.x) * e2.x, m2.y + __expf(l2.y) * e2.y);
    o1.y = pk(m2.z + __expf(l2.z) * e2.z, m2.w + __expf(l2.w) * e2.w);
    o1.z = pk(m3.x + __expf(l3.x) * e3.x, m3.y + __expf(l3.y) * e3.y);
    o1.w = pk(m3.z + __expf(l3.z) * e3.z, m3.w + __expf(l3.w) * e3.w);
    out[blockIdx.x * 512 + t]       = o0;
    out[blockIdx.x * 512 + 256 + t] = o1;
}

__global__ __launch_bounds__(256) void bl_cvt(
    const float4* __restrict__ in, uint4* __restrict__ out)
{
    const int t  = threadIdx.x;
    const int fb = blockIdx.x * 1024;
    const int ia = fb + 2 * t;
    const int ib = fb + 512 + 2 * t;
    const float4 v0 = in[ia], v1 = in[ia + 1], v2 = in[ib], v3 = in[ib + 1];
    uint4 o0, o1;
    o0.x = pk(v0.x, v0.y); o0.y = pk(v0.z, v0.w);
    o0.z = pk(v1.x, v1.y); o0.w = pk(v1.z, v1.w);
    o1.x = pk(v2.x, v2.y); o1.y = pk(v2.z, v2.w);
    o1.z = pk(v3.x, v3.y); o1.w = pk(v3.z, v3.w);
    out[blockIdx.x * 512 + t]       = o0;
    out[blockIdx.x * 512 + 256 + t] = o1;
}

// biases only: b0 (HID), b1..3 (3*HID), hb (100)
__global__ __launch_bounds__(256) void bl_small(
    const float* __restrict__ mu_b0, const float* __restrict__ ls_b0, const float* __restrict__ eps_b0,
    const float* __restrict__ mu_b,  const float* __restrict__ ls_b,  const float* __restrict__ eps_b,
    const float* __restrict__ mu_hb, const float* __restrict__ ls_hb, const float* __restrict__ eps_hb,
    float* __restrict__ b_all, float* __restrict__ hb)
{
    const int total = 4 * HID + NTASKS * OUT_DIM;
    const int i = blockIdx.x * blockDim.x + threadIdx.x;
    if (i >= total) return;
    if (i < HID) {
        b_all[i] = mu_b0[i] + __expf(ls_b0[i]) * eps_b0[i];
    } else if (i < 4 * HID) {
        const int j = i - HID;
        b_all[HID + j] = mu_b[j] + __expf(ls_b[j]) * eps_b[j];
    } else {
        const int j = i - 4 * HID;
        hb[j] = mu_hb[j] + __expf(ls_hb[j]) * eps_hb[j];
    }
}

// ---------------- fused GEMM + next-layer weight transform ----------------
// Waves 0-7: GEMM BM=256 BN=128 BK=64, 96KB dbuf. R14 change: 2 phases per
// K-tile instead of 4 — each phase reads a full kk-slice (8x ds_read_b128)
// and runs 16 MFMA in one setprio block. Barriers/K-tile: 8 -> 4 (3 BAR +
// 1 syncthreads); MFMA per barrier-pair doubles. Memory semantics unchanged
// (same dbuf slots, same stage targets, drain at syncthreads).
// Waves 8-9: round-6's store-then-load transform body (its 53.7us beat both
// "improved" pipelines), barrier sequence matched: 3xBAR + sync per tile.
#define BAR()        asm volatile("s_barrier" ::: "memory")
#define WAIT_LGKM0() do { asm volatile("s_waitcnt lgkmcnt(0)" ::: "memory"); __builtin_amdgcn_sched_barrier(0); } while (0)
#define RD_A(m, o)   (*(const bf16x8*)(ldsb + acur + (o) + (m)*2048))
#define RD_B(n, o)   (*(const bf16x8*)(ldsb + bcur + (o) + (n)*2048))
#define MFMA(d, va, vb) d = __builtin_amdgcn_mfma_f32_16x16x32_bf16(va, vb, d, 0, 0, 0)
#define STAGEI(i, kel, sl) \
    __builtin_amdgcn_global_load_lds((glb_u8*)(gsrc[i] + (kel)), \
        (lds_u8*)(ldsb + ldst[i] + (uint32_t)(sl) * smul[i]), 16, 0, 0)

template <int UPG, int TMODE>
__global__ __launch_bounds__(640, 1) void bl_gemm(
    const unsigned short* __restrict__ A,   // [4096][K] bf16
    const unsigned short* __restrict__ B,   // [2048][K] bf16
    const float* __restrict__ bias,         // [2048]
    unsigned short* __restrict__ C,         // [4096][2048] bf16
    int K,
    const float* __restrict__ tmu, const float* __restrict__ tls,
    const float* __restrict__ teps, void* __restrict__ tdst)
{
    __shared__ unsigned short lds[49152];   // 96 KB
    uint8_t* ldsb = (uint8_t*)lds;

    const int tid  = threadIdx.x;
    const int wave = tid >> 6;
    const int lane = tid & 63;
    const int NT = K >> 6;

    if (wave < 8) {
        // ================= GEMM path (waves 0-7) =================
        const int swz = ((blockIdx.x & 7) << 5) | (blockIdx.x >> 3);
        const int bm = swz >> 4;
        const int bn = swz & 15;
        const int wr = wave >> 1;
        const int wc = wave & 1;

        const int lr8 = lane >> 3;
        const int ss  = (lane & 7) ^ lr8;
        const unsigned short* gsrc[6];
        uint32_t ldst[6], smul[6];
        #pragma unroll
        for (int i = 0; i < 6; ++i) {
            const int c = wave * 6 + i;
            if (c < 32) {
                gsrc[i] = A + (size_t)(bm * 256 + c * 8 + lr8) * K + ss * 8;
                ldst[i] = (uint32_t)c * 1024u;
                smul[i] = 32768u;
            } else {
                gsrc[i] = B + (size_t)(bn * 128 + (c - 32) * 8 + lr8) * K + ss * 8;
                ldst[i] = 65536u + (uint32_t)(c - 32) * 1024u;
                smul[i] = 16384u;
            }
        }

        const int rA = wr * 64 + (lane & 15);
        const int rB = wc * 64 + (lane & 15);
        const int ks = lane >> 4;
        const uint32_t aoff0 = (uint32_t)(rA * 128 + ((ks       ^ (rA & 7)) * 16));
        const uint32_t aoff1 = (uint32_t)(rA * 128 + (((4 | ks) ^ (rA & 7)) * 16));
        const uint32_t boff0 = (uint32_t)(rB * 128 + ((ks       ^ (rB & 7)) * 16));
        const uint32_t boff1 = (uint32_t)(rB * 128 + (((4 | ks) ^ (rB & 7)) * 16));

        f32x4 acc[4][4] = {};

        STAGEI(0, 0, 0); STAGEI(1, 0, 0); STAGEI(2, 0, 0);
        STAGEI(3, 0, 0); STAGEI(4, 0, 0); STAGEI(5, 0, 0);
        __syncthreads();                                         // barrier #0

        for (int t = 0; t < NT; ++t) {
            const int cur = t & 1, nxt = cur ^ 1;
            const uint32_t acur = (uint32_t)cur * 32768u;
            const uint32_t bcur = 65536u + (uint32_t)cur * 16384u;
            const bool pf = (t + 1 < NT);
            const int ktn = (t + 1) << 6;

            bf16x8 a0, a1, a2, a3, b0, b1, b2, b3;

            // ---- phase A: full kk=0 slice, 16 MFMA ----
            a0 = RD_A(0, aoff0); a1 = RD_A(1, aoff0); a2 = RD_A(2, aoff0); a3 = RD_A(3, aoff0);
            b0 = RD_B(0, boff0); b1 = RD_B(1, boff0); b2 = RD_B(2, boff0); b3 = RD_B(3, boff0);
            if (pf) { STAGEI(0, ktn, nxt); STAGEI(1, ktn, nxt); STAGEI(2, ktn, nxt); }
            BAR(); WAIT_LGKM0();
            __builtin_amdgcn_s_setprio(1);
            MFMA(acc[0][0], a0, b0); MFMA(acc[0][1], a0, b1); MFMA(acc[0][2], a0, b2); MFMA(acc[0][3], a0, b3);
            MFMA(acc[1][0], a1, b0); MFMA(acc[1][1], a1, b1); MFMA(acc[1][2], a1, b2); MFMA(acc[1][3], a1, b3);
            MFMA(acc[2][0], a2, b0); MFMA(acc[2][1], a2, b1); MFMA(acc[2][2], a2, b2); MFMA(acc[2][3], a2, b3);
            MFMA(acc[3][0], a3, b0); MFMA(acc[3][1], a3, b1); MFMA(acc[3][2], a3, b2); MFMA(acc[3][3], a3, b3);
            __builtin_amdgcn_s_setprio(0);
            BAR();

            // ---- phase B: full kk=1 slice, 16 MFMA; dbuf swap drain ----
            a0 = RD_A(0, aoff1); a1 = RD_A(1, aoff1); a2 = RD_A(2, aoff1); a3 = RD_A(3, aoff1);
            b0 = RD_B(0, boff1); b1 = RD_B(1, boff1); b2 = RD_B(2, boff1); b3 = RD_B(3, boff1);
            if (pf) { STAGEI(3, ktn, nxt); STAGEI(4, ktn, nxt); STAGEI(5, ktn, nxt); }
            BAR(); WAIT_LGKM0();
            __builtin_amdgcn_s_setprio(1);
            MFMA(acc[0][0], a0, b0); MFMA(acc[0][1], a0, b1); MFMA(acc[0][2], a0, b2); MFMA(acc[0][3], a0, b3);
            MFMA(acc[1][0], a1, b0); MFMA(acc[1][1], a1, b1); MFMA(acc[1][2], a1, b2); MFMA(acc[1][3], a1, b3);
            MFMA(acc[2][0], a2, b0); MFMA(acc[2][1], a2, b1); MFMA(acc[2][2], a2, b2); MFMA(acc[2][3], a2, b3);
            MFMA(acc[3][0], a3, b0); MFMA(acc[3][1], a3, b1); MFMA(acc[3][2], a3, b2); MFMA(acc[3][3], a3, b3);
            __builtin_amdgcn_s_setprio(0);
            __syncthreads();
        }

        // epilogue
        const int col0 = bn * 128 + wc * 64 + (lane & 15);
        const int row0 = bm * 256 + wr * 64 + ((lane >> 4) << 2);
        #pragma unroll
        for (int n = 0; n < 4; ++n) {
            const int col = col0 + n * 16;
            const float bv = bias[col];
            #pragma unroll
            for (int m = 0; m < 4; ++m) {
                #pragma unroll
                for (int j = 0; j < 4; ++j) {
                    float v = acc[m][n][j] + bv;
                    v = v > 0.0f ? v : 0.0f;
                    C[(size_t)(row0 + m * 16 + j) * HID + col] = f2bf(v);
                }
            }
        }
    } else {
        // ===== transform path (waves 8-9, 128 threads), round-6 body =====
        // Per K-tile barrier sequence now: 3x BAR + 1x syncthreads.
        const int tw = tid - 512;                      // 0..127
        const float4* m4 = (const float4*)tmu;
        const float4* l4 = (const float4*)tls;
        const float4* e4 = (const float4*)teps;

        if (TMODE == 0) {
            ushort4* d4 = (ushort4*)tdst;
            const size_t base = (size_t)blockIdx.x * 4096;

            float4 pm[UPG], pl[UPG], pe[UPG];
            #pragma unroll
            for (int q = 0; q < UPG; ++q) {
                const size_t g = base + (size_t)q * 128 + tw;
                pm[q] = m4[g]; pl[q] = l4[g]; pe[q] = e4[g];
            }
            __syncthreads();                           // matches barrier #0

            for (int t = 0; t < NT; ++t) {
                #pragma unroll
                for (int q = 0; q < UPG; ++q) {
                    const size_t g = base + ((size_t)t * UPG + q) * 128 + tw;
                    ushort4 r;
                    r.x = f2bf(pm[q].x + __expf(pl[q].x) * pe[q].x);
                    r.y = f2bf(pm[q].y + __expf(pl[q].y) * pe[q].y);
                    r.z = f2bf(pm[q].z + __expf(pl[q].z) * pe[q].z);
                    r.w = f2bf(pm[q].w + __expf(pl[q].w) * pe[q].w);
                    d4[g] = r;
                }
                if (t + 1 < NT) {
                    #pragma unroll
                    for (int q = 0; q < UPG; ++q) {
                        const size_t g2 = base + ((size_t)(t + 1) * UPG + q) * 128 + tw;
                        pm[q] = m4[g2]; pl[q] = l4[g2]; pe[q] = e4[g2];
                    }
                }
                BAR(); BAR(); BAR();
                __syncthreads();
            }
        } else {
            // head weights -> f32: 200 float4-units/block
            const size_t base = (size_t)blockIdx.x * 200;
            __syncthreads();                           // matches barrier #0
            for (int t = 0; t < NT; ++t) {
                const int lo = t * 128 + tw;
                if (lo < 200) {
                    const size_t g = base + lo;
                    const float4 m = m4[g], l = l4[g], e = e4[g];
                    float4 r;
                    r.x = m.x + __expf(l.x) * e.x;
                    r.y = m.y + __expf(l.y) * e.y;
                    r.z = m.z + __expf(l.z) * e.z;
                    r.w = m.w + __expf(l.w) * e.w;
                    ((float4*)tdst)[g] = r;
                }
                BAR(); BAR(); BAR();
                __syncthreads();
            }
        }
    }
}

// ---------------- head ----------------
__global__ __launch_bounds__(256) void bl_head(
    const unsigned short* __restrict__ h,   // [4096][2048] bf16
    const float* __restrict__ hw,           // [10][10][2048] f32
    const float* __restrict__ hb,           // [10][10] f32
    const int* __restrict__ task,           // [4096] i32
    float* __restrict__ out)                // [4096][10] f32
{
    const int wave = threadIdx.x >> 6, lane = threadIdx.x & 63;
    const int b = blockIdx.x * 4 + wave;
    const int t = task[b];
    const float* w = hw + (size_t)t * OUT_DIM * HID;
    const unsigned short* hr = h + (size_t)b * HID;

    float acc[OUT_DIM];
    #pragma unroll
    for (int o = 0; o < OUT_DIM; ++o) acc[o] = 0.0f;

    #pragma unroll
    for (int i = 0; i < HID / 512; ++i) {
        const int k0 = (i * 64 + lane) * 8;
        const bf16x8 hv8 = *(const bf16x8*)(hr + k0);
        float hf[8];
        #pragma unroll
        for (int j = 0; j < 8; ++j) hf[j] = (float)hv8[j];
        #pragma unroll
        for (int o = 0; o < OUT_DIM; ++o) {
            const float4 w0 = *(const float4*)(w + (size_t)o * HID + k0);
            const float4 w1 = *(const float4*)(w + (size_t)o * HID + k0 + 4);
            acc[o] += hf[0]*w0.x + hf[1]*w0.y + hf[2]*w0.z + hf[3]*w0.w
                    + hf[4]*w1.x + hf[5]*w1.y + hf[6]*w1.z + hf[7]*w1.w;
        }
    }
    #pragma unroll
    for (int o = 0; o < OUT_DIM; ++o) {
        float v = acc[o];
        #pragma unroll
        for (int s = 32; s > 0; s >>= 1) v += __shfl_down(v, s, 64);
        if (lane == 0) out[(size_t)b * OUT_DIM + o] = v + hb[t * OUT_DIM + o];
    }
}

// ---------------- launch ----------------

extern "C" void kernel_launch(void* const* d_in, const int* in_sizes, int n_in,
                              void* d_out, int out_size, void* d_ws, size_t ws_size,
                              hipStream_t stream)
{
    const float* x      = (const float*)d_in[0];
    const float* mu_w0  = (const float*)d_in[1];
    const float* ls_w0  = (const float*)d_in[2];
    const float* mu_b0  = (const float*)d_in[3];
    const float* ls_b0  = (const float*)d_in[4];
    const float* mu_w   = (const float*)d_in[5];
    const float* ls_w   = (const float*)d_in[6];
    const float* mu_b   = (const float*)d_in[7];
    const float* ls_b   = (const float*)d_in[8];
    const float* mu_hw  = (const float*)d_in[9];
    const float* ls_hw  = (const float*)d_in[10];
    const float* mu_hb  = (const float*)d_in[11];
    const float* ls_hb  = (const float*)d_in[12];
    const float* eps_w0 = (const float*)d_in[13];
    const float* eps_b0 = (const float*)d_in[14];
    const float* eps_w  = (const float*)d_in[15];
    const float* eps_b  = (const float*)d_in[16];
    const float* eps_hw = (const float*)d_in[17];
    const float* eps_hb = (const float*)d_in[18];
    const int*   task   = (const int*)d_in[19];

    uint8_t* ws = (uint8_t*)d_ws;
    constexpr size_t HH     = (size_t)HID * HID;
    constexpr size_t X_OFF  = 0;
    constexpr size_t W0_OFF = X_OFF  + (size_t)BATCH * IN_DIM * 2;       // x bf16
    constexpr size_t W_OFF  = W0_OFF + (size_t)HID * IN_DIM * 2;         // w0 bf16
    constexpr size_t H0_OFF = W_OFF  + 3 * HH * 2;                       // w1..3 bf16
    constexpr size_t H1_OFF = H0_OFF + (size_t)BATCH * HID * 2;          // h ping
    constexpr size_t B_OFF  = H1_OFF + (size_t)BATCH * HID * 2;          // h pong
    constexpr size_t HW_OFF = B_OFF  + (size_t)4 * HID * 4;              // biases f32
    constexpr size_t HB_OFF = HW_OFF + (size_t)NTASKS * OUT_DIM * HID * 4;

    unsigned short* xbf = (unsigned short*)(ws + X_OFF);
    unsigned short* w0b = (unsigned short*)(ws + W0_OFF);
    unsigned short* wb  = (unsigned short*)(ws + W_OFF);
    unsigned short* h0  = (unsigned short*)(ws + H0_OFF);
    unsigned short* h1  = (unsigned short*)(ws + H1_OFF);
    float* ball = (float*)(ws + B_OFF);
    float* hwf  = (float*)(ws + HW_OFF);
    float* hbf  = (float*)(ws + HB_OFF);

    bl_cvt<<<BATCH * IN_DIM / 4096, 256, 0, stream>>>((const float4*)x, (uint4*)xbf);
    bl_transform<<<HID * IN_DIM / 4096, 256, 0, stream>>>(
        (const float4*)mu_w0, (const float4*)ls_w0, (const float4*)eps_w0, (uint4*)w0b);
    bl_small<<<(4 * HID + NTASKS * OUT_DIM + 255) / 256, 256, 0, stream>>>(
        mu_b0, ls_b0, eps_b0, mu_b, ls_b, eps_b, mu_hb, ls_hb, eps_hb, ball, hbf);

    // GEMM_i fuses the transform of layer i+1's weights (or head weights).
    bl_gemm<2, 0><<<256, 640, 0, stream>>>(xbf, w0b, ball, h0, IN_DIM,
        mu_w, ls_w, eps_w, (void*)wb);                               // w1 (NT=16, upg=2)
    bl_gemm<1, 0><<<256, 640, 0, stream>>>(h0, wb, ball + HID, h1, HID,
        mu_w + HH, ls_w + HH, eps_w + HH, (void*)(wb + HH));         // w2
    bl_gemm<1, 0><<<256, 640, 0, stream>>>(h1, wb + HH, ball + 2 * HID, h0, HID,
        mu_w + 2 * HH, ls_w + 2 * HH, eps_w + 2 * HH, (void*)(wb + 2 * HH)); // w3
    bl_gemm<1, 1><<<256, 640, 0, stream>>>(h0, wb + 2 * HH, ball + 3 * HID, h1, HID,
        mu_hw, ls_hw, eps_hw, (void*)hwf);                           // head weights f32

    bl_head<<<BATCH / 4, 256, 0, stream>>>(h1, hwf, hbf, task, (float*)d_out);
}